// Round 5
// baseline (7495.245 us; speedup 1.0000x reference)
//
#include <hip/hip_runtime.h>
#include <hip/hip_bf16.h>

typedef __hip_bfloat16 bf16;

#define T_ 8
#define N_ 1152
#define C_ 768
#define H_ 12
#define DH_ 64
#define MLP_ 3072
#define LRU_ 768
#define NIMG_ 1024
#define M_ (T_*N_)       // 9216 tokens
#define NCH 4
#define CHM (M_/NCH)     // 2304 rows per MLP chunk; CHM*MLP == M*C exactly

__device__ __forceinline__ float b2f(bf16 v){ return __bfloat162float(v); }
__device__ __forceinline__ bf16  f2b(float f){ return __float2bfloat16(f); }
__device__ __forceinline__ float us2f(unsigned short u){
  union { unsigned int i; float f; } c; c.i = ((unsigned int)u) << 16; return c.f;
}
__device__ __forceinline__ float gelu_tanh(float x){
  float x3 = x*x*x;
  return 0.5f*x*(1.f + tanhf(0.7978845608028654f*(x + 0.044715f*x3)));
}
union U16x8 { uint4 u4; unsigned short s[8]; };

// ---------------- norm: one wave per token; fp32 in, bf16 out ----------------
// LN=0: rms_norm with (1+scale); LN=1: layer_norm with scale,bias
template<int LN>
__global__ __launch_bounds__(256)
void norm_kernel(const float* __restrict__ inp, const float* __restrict__ s,
                 const float* __restrict__ b, bf16* __restrict__ out) {
  int wid  = threadIdx.x >> 6;
  int lane = threadIdx.x & 63;
  int tok  = blockIdx.x * 4 + wid;
  float v[12];
  float sum = 0.f, sq = 0.f;
  #pragma unroll
  for (int i = 0; i < 12; i++) {
    int c = lane + i * 64;
    float x = inp[(size_t)tok*C_ + c];
    v[i] = x; sum += x; sq += x * x;
  }
  #pragma unroll
  for (int o = 32; o > 0; o >>= 1) {
    sum += __shfl_xor(sum, o, 64);
    sq  += __shfl_xor(sq, o, 64);
  }
  float scale, mean = 0.f;
  if (LN) {
    mean = sum * (1.f / C_);
    float var = sq * (1.f / C_) - mean * mean;
    scale = rsqrtf(var + 1e-6f);
  } else {
    scale = rsqrtf(sq * (1.f / C_) + 1e-6f);
  }
  #pragma unroll
  for (int i = 0; i < 12; i++) {
    int c = lane + i * 64;
    float sc = s[c];
    float r;
    if (LN) r = (v[i] - mean) * scale * sc + b[c];
    else    r = v[i] * scale * (1.f + sc);
    out[(size_t)tok*C_ + c] = f2b(r);
  }
}

// ---------------- tiled GEMM: bf16 A, fp32 weights, fp32 acc ----------------
// ACT: 0 none, 1 gelu (before residual). RES: 0 none, 1 fp32 residual.
// OUTF: 0 bf16 out, 1 fp32 out.
#define BM 128
#define BN 64
#define BK 16

template<int ACT, int RES, int OUTF>
__global__ __launch_bounds__(256)
void gemm_kernel(const bf16* __restrict__ A, const float* __restrict__ Bw,
                 const float* __restrict__ bias, const float* __restrict__ resid,
                 void* __restrict__ outp, int K, int Nd) {
  __shared__ float As[BK][BM];
  __shared__ float Bs[BK][BN];
  int tid = threadIdx.x;
  int tx = tid & 15, ty = tid >> 4;
  int row0 = blockIdx.y * BM;
  int col0 = blockIdx.x * BN;
  float acc[8][4];
  #pragma unroll
  for (int i = 0; i < 8; i++)
    #pragma unroll
    for (int j = 0; j < 4; j++) acc[i][j] = 0.f;

  int ar = tid >> 1;          // 0..127
  int ak = (tid & 1) * 8;     // 0 or 8
  int br = tid >> 4;          // 0..15
  int bc = (tid & 15) * 4;    // 0..60

  for (int k0 = 0; k0 < K; k0 += BK) {
    const bf16* ap = A + (size_t)(row0 + ar) * K + k0 + ak;
    U16x8 au; au.u4 = *(const uint4*)ap;
    #pragma unroll
    for (int i = 0; i < 8; i++) As[ak+i][ar] = us2f(au.s[i]);
    const float* bp = Bw + (size_t)(k0 + br) * Nd + col0 + bc;
    float4 bv = *(const float4*)bp;
    Bs[br][bc+0] = bv.x; Bs[br][bc+1] = bv.y;
    Bs[br][bc+2] = bv.z; Bs[br][bc+3] = bv.w;
    __syncthreads();
    #pragma unroll
    for (int kk = 0; kk < BK; kk++) {
      float a[8], bb[4];
      #pragma unroll
      for (int i = 0; i < 8; i++) a[i] = As[kk][ty*8 + i];
      #pragma unroll
      for (int j = 0; j < 4; j++) bb[j] = Bs[kk][tx*4 + j];
      #pragma unroll
      for (int i = 0; i < 8; i++)
        #pragma unroll
        for (int j = 0; j < 4; j++) acc[i][j] += a[i] * bb[j];
    }
    __syncthreads();
  }

  float* outF = (float*)outp;
  bf16*  outB = (bf16*)outp;
  #pragma unroll
  for (int i = 0; i < 8; i++) {
    int row = row0 + ty*8 + i;
    size_t base = (size_t)row * Nd + col0 + tx*4;
    #pragma unroll
    for (int j = 0; j < 4; j++) {
      int col = col0 + tx*4 + j;
      float v = acc[i][j] + bias[col];
      if (ACT == 1) v = gelu_tanh(v);
      if (RES == 1) v += resid[base + j];
      if (OUTF) outF[base + j] = v;
      else      outB[base + j] = f2b(v);
    }
  }
}

// ---------------- dual GEMM: g = gelu(A@B0+b0)*(A@B1+b1), bf16 out ----------------
__global__ __launch_bounds__(256)
void gemm_dual_kernel(const bf16* __restrict__ A, const float* __restrict__ B0w,
                      const float* __restrict__ B1w, const float* __restrict__ bias0,
                      const float* __restrict__ bias1, bf16* __restrict__ outp,
                      int K, int Nd) {
  __shared__ float As[BK][BM];
  __shared__ float Bs0[BK][BN];
  __shared__ float Bs1[BK][BN];
  int tid = threadIdx.x;
  int tx = tid & 15, ty = tid >> 4;
  int row0 = blockIdx.y * BM;
  int col0 = blockIdx.x * BN;
  float acc0[8][4], acc1[8][4];
  #pragma unroll
  for (int i = 0; i < 8; i++)
    #pragma unroll
    for (int j = 0; j < 4; j++) { acc0[i][j] = 0.f; acc1[i][j] = 0.f; }

  int ar = tid >> 1;
  int ak = (tid & 1) * 8;
  int br = tid >> 4;
  int bc = (tid & 15) * 4;

  for (int k0 = 0; k0 < K; k0 += BK) {
    const bf16* ap = A + (size_t)(row0 + ar) * K + k0 + ak;
    U16x8 au; au.u4 = *(const uint4*)ap;
    #pragma unroll
    for (int i = 0; i < 8; i++) As[ak+i][ar] = us2f(au.s[i]);
    size_t boff = (size_t)(k0 + br) * Nd + col0 + bc;
    float4 b0v4 = *(const float4*)(B0w + boff);
    float4 b1v4 = *(const float4*)(B1w + boff);
    Bs0[br][bc+0] = b0v4.x; Bs0[br][bc+1] = b0v4.y;
    Bs0[br][bc+2] = b0v4.z; Bs0[br][bc+3] = b0v4.w;
    Bs1[br][bc+0] = b1v4.x; Bs1[br][bc+1] = b1v4.y;
    Bs1[br][bc+2] = b1v4.z; Bs1[br][bc+3] = b1v4.w;
    __syncthreads();
    #pragma unroll
    for (int kk = 0; kk < BK; kk++) {
      float a[8], b0v[4], b1v[4];
      #pragma unroll
      for (int i = 0; i < 8; i++) a[i] = As[kk][ty*8 + i];
      #pragma unroll
      for (int j = 0; j < 4; j++) { b0v[j] = Bs0[kk][tx*4 + j]; b1v[j] = Bs1[kk][tx*4 + j]; }
      #pragma unroll
      for (int i = 0; i < 8; i++)
        #pragma unroll
        for (int j = 0; j < 4; j++) {
          acc0[i][j] += a[i] * b0v[j];
          acc1[i][j] += a[i] * b1v[j];
        }
    }
    __syncthreads();
  }

  #pragma unroll
  for (int i = 0; i < 8; i++) {
    int row = row0 + ty*8 + i;
    size_t base = (size_t)row * Nd + col0 + tx*4;
    #pragma unroll
    for (int j = 0; j < 4; j++) {
      int col = col0 + tx*4 + j;
      float d0 = acc0[i][j] + bias0[col];
      float d1 = acc1[i][j] + bias1[col];
      outp[base + j] = f2b(gelu_tanh(d0) * d1);
    }
  }
}

// ---------------- causal depthwise temporal conv (width 4) ----------------
__global__ __launch_bounds__(256)
void conv_kernel(const bf16* __restrict__ u0, const float* __restrict__ cw,
                 const float* __restrict__ cb, bf16* __restrict__ uc) {
  int idx = blockIdx.x * 256 + threadIdx.x;   // over M_*LRU_
  int ch  = idx % LRU_;
  int tok = idx / LRU_;
  int n = tok % N_;
  int t = tok / N_;
  float acc = cb[ch];
  #pragma unroll
  for (int i = 0; i < 4; i++) {
    int tt = t - 3 + i;
    if (tt >= 0)
      acc += cw[i*LRU_ + ch] * b2f(u0[(size_t)(tt*N_ + n)*LRU_ + ch]);
  }
  uc[idx] = f2b(acc);
}

// ---------------- RG-LRU gates ----------------
__global__ __launch_bounds__(64)
void gates_kernel(const bf16* __restrict__ uc, const float* __restrict__ igw,
                  const float* __restrict__ igb, const float* __restrict__ agw,
                  const float* __restrict__ agb, const float* __restrict__ ap,
                  bf16* __restrict__ a_out, bf16* __restrict__ nx_out) {
  int bid = blockIdx.x;          // tok*H + h
  int h   = bid % H_;
  int tok = bid / H_;
  int t   = tok / N_;
  int e   = threadIdx.x;         // 0..63
  __shared__ float us[64];
  size_t base = (size_t)tok * LRU_ + h * DH_;
  us[e] = b2f(uc[base + e]);
  __syncthreads();
  float dx = 0.f, da = 0.f;
  const float* wi = igw + (size_t)h * DH_ * DH_ + e;
  const float* wa = agw + (size_t)h * DH_ * DH_ + e;
  #pragma unroll
  for (int d = 0; d < 64; d++) {
    float ud = us[d];
    dx += ud * wi[d * 64];
    da += ud * wa[d * 64];
  }
  dx += igb[h*DH_ + e];
  da += agb[h*DH_ + e];
  float gx = 1.f / (1.f + expf(-dx));
  float ga = 1.f / (1.f + expf(-da));
  float apv = ap[h*DH_ + e];
  float sp = (apv > 20.f) ? apv : log1pf(expf(apv));
  float log_a = -8.f * ga * sp;
  float a = expf(log_a);
  float mult = sqrtf(fmaxf(1.f - expf(2.f * log_a), 0.f));
  if (t == 0) { a = 0.f; mult = 1.f; }
  a_out[base + e]  = f2b(a);
  nx_out[base + e] = f2b(us[e] * gx * mult);
}

// ---------------- RG-LRU scan over t=8, fused h*y ----------------
__global__ __launch_bounds__(256)
void scan_kernel(const bf16* __restrict__ a, const bf16* __restrict__ nx,
                 const bf16* __restrict__ y, bf16* __restrict__ hy) {
  int idx = blockIdx.x * 256 + threadIdx.x;  // over N_*LRU_
  int n  = idx / LRU_;
  int ch = idx % LRU_;
  float h = 0.f;
  #pragma unroll
  for (int t = 0; t < T_; t++) {
    size_t p = (size_t)(t*N_ + n) * LRU_ + ch;
    h = b2f(a[p]) * h + b2f(nx[p]);
    hy[p] = f2b(h * b2f(y[p]));
  }
}

// ---------------- attention: one wave per (t, h, q-row), two-pass softmax ----------------
// mask_image2image: q<1024 attends only to keys 1024..1151; q>=1024 attends to all.
#define WPB 4
__global__ __launch_bounds__(256)
void attn_kernel(const bf16* __restrict__ q, const bf16* __restrict__ k,
                 const bf16* __restrict__ v, bf16* __restrict__ sa) {
  __shared__ float sc[WPB][N_];
  int wid  = threadIdx.x >> 6;
  int lane = threadIdx.x & 63;
  int gw = blockIdx.x * WPB + wid;   // ((t*H + h)*N + qn)
  int qn = gw % N_;
  int th = gw / N_;
  int h = th % H_;
  int t = th / H_;
  size_t qoff = (size_t)(t*N_ + qn) * C_ + h * DH_;
  float qv = b2f(q[qoff + lane]);
  int k0 = (qn < NIMG_) ? NIMG_ : 0;
  int nk = N_ - k0;
  const bf16* kb = k + (size_t)(t*N_ + k0) * C_ + h * DH_ + lane;
  float* s = sc[wid];
  for (int kk = 0; kk < nk; kk++) {
    float p = qv * b2f(kb[(size_t)kk * C_]);
    #pragma unroll
    for (int o = 32; o > 0; o >>= 1) p += __shfl_xor(p, o, 64);
    if (lane == 0) s[kk] = p * 0.125f;
  }
  __syncthreads();
  float mx = -3.4e38f;
  for (int kk = lane; kk < nk; kk += 64) mx = fmaxf(mx, s[kk]);
  #pragma unroll
  for (int o = 32; o > 0; o >>= 1) mx = fmaxf(mx, __shfl_xor(mx, o, 64));
  float sum = 0.f;
  for (int kk = lane; kk < nk; kk += 64) {
    float e = expf(s[kk] - mx);
    s[kk] = e; sum += e;
  }
  #pragma unroll
  for (int o = 32; o > 0; o >>= 1) sum += __shfl_xor(sum, o, 64);
  __syncthreads();
  float inv = 1.f / sum;
  const bf16* vb = v + (size_t)(t*N_ + k0) * C_ + h * DH_ + lane;
  float o = 0.f;
  for (int kk = 0; kk < nk; kk++) o += s[kk] * b2f(vb[(size_t)kk * C_]);
  sa[qoff + lane] = f2b(o * inv);
}

extern "C" void kernel_launch(void* const* d_in, const int* in_sizes, int n_in,
                              void* d_out, int out_size, void* d_ws, size_t ws_size,
                              hipStream_t stream) {
  (void)in_sizes; (void)n_in; (void)out_size; (void)ws_size;
  const float* x        = (const float*)d_in[0];
  const float* tpre     = (const float*)d_in[1];
  const float* w_y      = (const float*)d_in[2];
  const float* b_y      = (const float*)d_in[3];
  const float* w_x      = (const float*)d_in[4];
  const float* b_x      = (const float*)d_in[5];
  const float* conv_w   = (const float*)d_in[6];
  const float* conv_b   = (const float*)d_in[7];
  const float* a_param  = (const float*)d_in[8];
  const float* ig_w     = (const float*)d_in[9];
  const float* ig_b     = (const float*)d_in[10];
  const float* ag_w     = (const float*)d_in[11];
  const float* ag_b     = (const float*)d_in[12];
  const float* w_out    = (const float*)d_in[13];
  const float* b_out    = (const float*)d_in[14];
  const float* cpre     = (const float*)d_in[15];
  const float* ffw_up_w = (const float*)d_in[16];
  const float* ffw_up_b = (const float*)d_in[17];
  const float* ffw_dn_w = (const float*)d_in[18];
  const float* ffw_dn_b = (const float*)d_in[19];
  const float* ln1_s    = (const float*)d_in[20];
  const float* ln1_b    = (const float*)d_in[21];
  const float* wq       = (const float*)d_in[22];
  const float* bq       = (const float*)d_in[23];
  const float* wk       = (const float*)d_in[24];
  const float* bk       = (const float*)d_in[25];
  const float* wv       = (const float*)d_in[26];
  const float* bv       = (const float*)d_in[27];
  const float* wo       = (const float*)d_in[28];
  const float* bo       = (const float*)d_in[29];
  const float* ln2_s    = (const float*)d_in[30];
  const float* ln2_b    = (const float*)d_in[31];
  const float* mlp_w1   = (const float*)d_in[32];
  const float* mlp_b1   = (const float*)d_in[33];
  const float* mlp_w2   = (const float*)d_in[34];
  const float* mlp_b2   = (const float*)d_in[35];

  const size_t MC = (size_t)M_ * C_;
  // workspace (~110.6 MiB): B0,B1,B2,BV bf16 M*C; F0,F1 fp32 M*C.
  bf16* B0 = (bf16*)d_ws;
  bf16* B1 = B0 + MC;
  bf16* B2 = B1 + MC;
  bf16* BV = B2 + MC;
  float* F0 = (float*)(BV + MC);
  float* F1 = F0 + MC;
  float* outF = (float*)d_out;   // fp32 output (reference output dtype)

  dim3 blk(256);
  dim3 g768(C_/BN, M_/BM);       // (12, 72)
  dim3 gch768(C_/BN, CHM/BM);    // (12, 18)
  dim3 gchmlp(MLP_/BN, CHM/BM);  // (48, 18)

  // ---- temporal RG-LRU block ----
  norm_kernel<0><<<M_/4, blk, 0, stream>>>(x, tpre, nullptr, B0);                       // xn -> B0
  gemm_kernel<1,0,0><<<g768, blk, 0, stream>>>(B0, w_y, b_y, nullptr, B1, C_, C_);      // y  -> B1
  gemm_kernel<0,0,0><<<g768, blk, 0, stream>>>(B0, w_x, b_x, nullptr, B2, C_, C_);      // u0 -> B2  [xn dead]
  conv_kernel<<<(M_*LRU_)/256, blk, 0, stream>>>(B2, conv_w, conv_b, B0);               // uc -> B0  [u0 dead]
  gates_kernel<<<M_*H_, 64, 0, stream>>>(B0, ig_w, ig_b, ag_w, ag_b, a_param, B2, BV);  // a->B2, nx->BV [uc dead]
  scan_kernel<<<(N_*LRU_)/256, blk, 0, stream>>>(B2, BV, B1, B0);                       // hy -> B0  [a,nx,y dead]
  gemm_kernel<0,1,1><<<g768, blk, 0, stream>>>(B0, w_out, b_out, x, F0, LRU_, C_);      // resid -> F0 (fp32)
  // ---- gated MLP (chunked; B2 holds one CHM x MLP bf16 chunk == M*C elems) ----
  norm_kernel<0><<<M_/4, blk, 0, stream>>>(F0, cpre, nullptr, B0);                      // z -> B0
  for (int r = 0; r < NCH; r++) {
    size_t ro = (size_t)r * CHM;
    gemm_dual_kernel<<<gchmlp, blk, 0, stream>>>(B0 + ro*C_, ffw_up_w, ffw_up_w + (size_t)C_*MLP_,
                                                 ffw_up_b, ffw_up_b + MLP_, B2, C_, MLP_);   // g -> B2
    gemm_kernel<0,1,1><<<gch768, blk, 0, stream>>>(B2, ffw_dn_w, ffw_dn_b, F0 + ro*C_,
                                                   F1 + ro*C_, MLP_, C_);               // xs chunk -> F1 (fp32)
  }
  // ---- spatial ViT block ----
  norm_kernel<1><<<M_/4, blk, 0, stream>>>(F1, ln1_s, ln1_b, B0);                       // y1 -> B0 [z dead]
  gemm_kernel<0,0,0><<<g768, blk, 0, stream>>>(B0, wq, bq, nullptr, B1, C_, C_);        // q -> B1
  gemm_kernel<0,0,0><<<g768, blk, 0, stream>>>(B0, wk, bk, nullptr, B2, C_, C_);        // k -> B2
  gemm_kernel<0,0,0><<<g768, blk, 0, stream>>>(B0, wv, bv, nullptr, BV, C_, C_);        // v -> BV
  attn_kernel<<<(T_*H_*N_)/WPB, blk, 0, stream>>>(B1, B2, BV, B0);                      // sa -> B0 [y1 dead]
  gemm_kernel<0,1,1><<<g768, blk, 0, stream>>>(B0, wo, bo, F1, F0, C_, C_);             // xs2 = sa@wo + xs -> F0 [old resid dead]
  norm_kernel<1><<<M_/4, blk, 0, stream>>>(F0, ln2_s, ln2_b, B1);                       // y2 -> B1 [q dead]
  for (int r = 0; r < NCH; r++) {
    size_t ro = (size_t)r * CHM;
    gemm_kernel<1,0,0><<<gchmlp, blk, 0, stream>>>(B1 + ro*C_, mlp_w1, mlp_b1, nullptr,
                                                   B2, C_, MLP_);                       // m1 chunk -> B2 [k dead]
    gemm_kernel<0,1,1><<<gch768, blk, 0, stream>>>(B2, mlp_w2, mlp_b2, F0 + ro*C_,
                                                   outF + ro*C_, MLP_, C_);             // out chunk (fp32)
  }
}

// Round 6
// 1381.171 us; speedup vs baseline: 5.4267x; 5.4267x over previous
//
#include <hip/hip_runtime.h>
#include <hip/hip_bf16.h>

typedef __hip_bfloat16 bf16;
typedef __attribute__((ext_vector_type(4))) float f32x4;
typedef __attribute__((ext_vector_type(8))) short short8;

#define T_ 8
#define N_ 1152
#define C_ 768
#define H_ 12
#define DH_ 64
#define MLP_ 3072
#define LRU_ 768
#define NIMG_ 1024
#define M_ (T_*N_)       // 9216 tokens

__device__ __forceinline__ float b2f(bf16 v){ return __bfloat162float(v); }
__device__ __forceinline__ bf16  f2b(float f){ return __float2bfloat16(f); }
__device__ __forceinline__ float gelu_tanh(float x){
  float x3 = x*x*x;
  return 0.5f*x*(1.f + tanhf(0.7978845608028654f*(x + 0.044715f*x3)));
}
__device__ __forceinline__ void gll16(const void* g, void* l) {
  __builtin_amdgcn_global_load_lds((const __attribute__((address_space(1))) void*)g,
                                   (__attribute__((address_space(3))) void*)l, 16, 0, 0);
}
__device__ __forceinline__ f32x4 mfma16(short8 a, short8 b, f32x4 c) {
  return __builtin_amdgcn_mfma_f32_16x16x32_bf16(a, b, c, 0, 0, 0);
}

// ---------------- transpose-convert: W[K][N] fp32 -> Wt[(n*rs+ro)][K] bf16 ----------------
__global__ __launch_bounds__(256)
void convertT(const float* __restrict__ W, bf16* __restrict__ Wt, int Kd, int Nd,
              int rs, int ro) {
  __shared__ float tile[64][65];
  int k0 = blockIdx.y * 64, n0 = blockIdx.x * 64;
  int tid = threadIdx.x;
  int c = tid & 63, rr = tid >> 6;
  #pragma unroll
  for (int i = 0; i < 16; i++) {
    int r = rr * 16 + i;
    tile[r][c] = W[(size_t)(k0 + r) * Nd + n0 + c];
  }
  __syncthreads();
  #pragma unroll
  for (int i = 0; i < 16; i++) {
    int n = rr * 16 + i;
    Wt[(size_t)((n0 + n) * rs + ro) * Kd + k0 + c] = f2b(tile[c][n]);
  }
}

// ---------------- MFMA GEMM: A[M,K] bf16 x Wt[N,K] bf16 -> out[M,N] ----------------
// EPI: 0 = bf16 out (+bias, opt gelu); 1 = fp32 out = v+bias(+gelu)+resid (resid may equal out);
//      2 = bf16 out scattered to V-transposed layout [t,h][d][n];
//      3 = interleaved gated-FFW: out[row][col>>1] = gelu(even+b0)*(odd+b1), bf16, width Nd/2
template<int EPI, int ACT>
__global__ __launch_bounds__(256)
void mgemm(const bf16* __restrict__ A, const bf16* __restrict__ Wt,
           const float* __restrict__ bias, const float* __restrict__ resid,
           void* __restrict__ outp, int K, int Nd) {
  __shared__ bf16 As[128][32];
  __shared__ bf16 Bs[128][32];
  int tid = threadIdx.x;
  int wave = tid >> 6, lane = tid & 63;
  int wm = wave >> 1, wn = wave & 1;
  int ln15 = lane & 15, quad = lane >> 4;
  int row0 = blockIdx.y * 128, col0 = blockIdx.x * 128;
  const bf16* ag = A  + (size_t)(row0 + wave*32 + (lane>>2)) * K + (lane&3)*8;
  const bf16* bg = Wt + (size_t)(col0 + wave*32 + (lane>>2)) * K + (lane&3)*8;
  f32x4 zero = {0.f, 0.f, 0.f, 0.f};
  f32x4 acc[4][4];
  #pragma unroll
  for (int i = 0; i < 4; i++)
    #pragma unroll
    for (int j = 0; j < 4; j++) acc[i][j] = zero;

  for (int k0 = 0; k0 < K; k0 += 32) {
    gll16(ag + k0,          &As[wave*32][0]);
    gll16(ag + 16*K + k0,   &As[wave*32 + 16][0]);
    gll16(bg + k0,          &Bs[wave*32][0]);
    gll16(bg + 16*K + k0,   &Bs[wave*32 + 16][0]);
    __syncthreads();
    short8 af[4], bf[4];
    #pragma unroll
    for (int i = 0; i < 4; i++)
      af[i] = *(const short8*)&As[wm*64 + i*16 + ln15][quad*8];
    #pragma unroll
    for (int i = 0; i < 4; i++)
      bf[i] = *(const short8*)&Bs[wn*64 + i*16 + ln15][quad*8];
    #pragma unroll
    for (int i = 0; i < 4; i++)
      #pragma unroll
      for (int j = 0; j < 4; j++)
        acc[i][j] = mfma16(af[i], bf[j], acc[i][j]);
    __syncthreads();
  }

  #pragma unroll
  for (int i = 0; i < 4; i++) {
    #pragma unroll
    for (int j = 0; j < 4; j++) {
      int col = col0 + wn*64 + j*16 + ln15;
      float bv = (EPI == 3) ? bias[(col & 1) * (Nd >> 1) + (col >> 1)] : bias[col];
      #pragma unroll
      for (int r = 0; r < 4; r++) {
        int row = row0 + wm*64 + i*16 + quad*4 + r;
        float v = acc[i][j][r] + bv;
        if (EPI == 3) {
          float pv = __shfl_xor(v, 1, 64);
          if ((lane & 1) == 0)
            ((bf16*)outp)[(size_t)row * (Nd >> 1) + (col >> 1)] = f2b(gelu_tanh(v) * pv);
        } else {
          if (ACT) v = gelu_tanh(v);
          if (EPI == 0) {
            ((bf16*)outp)[(size_t)row * Nd + col] = f2b(v);
          } else if (EPI == 1) {
            size_t o = (size_t)row * Nd + col;
            ((float*)outp)[o] = v + resid[o];
          } else if (EPI == 2) {
            int tt = row / N_; int nn = row - tt * N_;
            ((bf16*)outp)[(((size_t)tt * H_ + (col >> 6)) * 64 + (col & 63)) * N_ + nn] = f2b(v);
          }
        }
      }
    }
  }
}

// ---------------- norm: one wave per token; fp32 in, bf16 out ----------------
template<int LN>
__global__ __launch_bounds__(256)
void norm_kernel(const float* __restrict__ inp, const float* __restrict__ s,
                 const float* __restrict__ b, bf16* __restrict__ out) {
  int wid  = threadIdx.x >> 6;
  int lane = threadIdx.x & 63;
  int tok  = blockIdx.x * 4 + wid;
  float v[12];
  float sum = 0.f, sq = 0.f;
  #pragma unroll
  for (int i = 0; i < 12; i++) {
    int c = lane + i * 64;
    float x = inp[(size_t)tok*C_ + c];
    v[i] = x; sum += x; sq += x * x;
  }
  #pragma unroll
  for (int o = 32; o > 0; o >>= 1) {
    sum += __shfl_xor(sum, o, 64);
    sq  += __shfl_xor(sq, o, 64);
  }
  float scale, mean = 0.f;
  if (LN) {
    mean = sum * (1.f / C_);
    float var = sq * (1.f / C_) - mean * mean;
    scale = rsqrtf(var + 1e-6f);
  } else {
    scale = rsqrtf(sq * (1.f / C_) + 1e-6f);
  }
  #pragma unroll
  for (int i = 0; i < 12; i++) {
    int c = lane + i * 64;
    float sc = s[c];
    float r;
    if (LN) r = (v[i] - mean) * scale * sc + b[c];
    else    r = v[i] * scale * (1.f + sc);
    out[(size_t)tok*C_ + c] = f2b(r);
  }
}

// ---------------- causal depthwise temporal conv (width 4) ----------------
__global__ __launch_bounds__(256)
void conv_kernel(const bf16* __restrict__ u0, const float* __restrict__ cw,
                 const float* __restrict__ cb, bf16* __restrict__ uc) {
  int idx = blockIdx.x * 256 + threadIdx.x;
  int ch  = idx % LRU_;
  int tok = idx / LRU_;
  int n = tok % N_;
  int t = tok / N_;
  float acc = cb[ch];
  #pragma unroll
  for (int i = 0; i < 4; i++) {
    int tt = t - 3 + i;
    if (tt >= 0)
      acc += cw[i*LRU_ + ch] * b2f(u0[(size_t)(tt*N_ + n)*LRU_ + ch]);
  }
  uc[idx] = f2b(acc);
}

// ---------------- RG-LRU gates ----------------
__global__ __launch_bounds__(64)
void gates_kernel(const bf16* __restrict__ uc, const float* __restrict__ igw,
                  const float* __restrict__ igb, const float* __restrict__ agw,
                  const float* __restrict__ agb, const float* __restrict__ ap,
                  bf16* __restrict__ a_out, bf16* __restrict__ nx_out) {
  int bid = blockIdx.x;
  int h   = bid % H_;
  int tok = bid / H_;
  int t   = tok / N_;
  int e   = threadIdx.x;
  __shared__ float us[64];
  size_t base = (size_t)tok * LRU_ + h * DH_;
  us[e] = b2f(uc[base + e]);
  __syncthreads();
  float dx = 0.f, da = 0.f;
  const float* wi = igw + (size_t)h * DH_ * DH_ + e;
  const float* wa = agw + (size_t)h * DH_ * DH_ + e;
  #pragma unroll
  for (int d = 0; d < 64; d++) {
    float ud = us[d];
    dx += ud * wi[d * 64];
    da += ud * wa[d * 64];
  }
  dx += igb[h*DH_ + e];
  da += agb[h*DH_ + e];
  float gx = 1.f / (1.f + expf(-dx));
  float ga = 1.f / (1.f + expf(-da));
  float apv = ap[h*DH_ + e];
  float sp = (apv > 20.f) ? apv : log1pf(expf(apv));
  float log_a = -8.f * ga * sp;
  float a = expf(log_a);
  float mult = sqrtf(fmaxf(1.f - expf(2.f * log_a), 0.f));
  if (t == 0) { a = 0.f; mult = 1.f; }
  a_out[base + e]  = f2b(a);
  nx_out[base + e] = f2b(us[e] * gx * mult);
}

// ---------------- RG-LRU scan over t=8, fused h*y ----------------
__global__ __launch_bounds__(256)
void scan_kernel(const bf16* __restrict__ a, const bf16* __restrict__ nx,
                 const bf16* __restrict__ y, bf16* __restrict__ hy) {
  int idx = blockIdx.x * 256 + threadIdx.x;
  int n  = idx / LRU_;
  int ch = idx % LRU_;
  float h = 0.f;
  #pragma unroll
  for (int t = 0; t < T_; t++) {
    size_t p = (size_t)(t*N_ + n) * LRU_ + ch;
    h = b2f(a[p]) * h + b2f(nx[p]);
    hy[p] = f2b(h * b2f(y[p]));
  }
}

// ---------------- flash attention (MFMA), mask_image2image ----------------
// grid: x = 18 q-blocks of 64 queries, y = t*H + h. block 256 (4 waves x 16 q).
// Vt global layout: [t*H+h][64 d][1152 n] bf16 (written by v-proj EPI2).
__global__ __launch_bounds__(256)
void fattn(const bf16* __restrict__ Q, const bf16* __restrict__ Kg,
           const bf16* __restrict__ Vt, bf16* __restrict__ O) {
  __shared__ bf16 Ks[128][64];      // [key][d]
  __shared__ bf16 VTs[64][128];     // [d][key]
  __shared__ bf16 Ps[4][16][128];   // per-wave P
  int qb = blockIdx.x, th = blockIdx.y;
  int h = th % H_, t = th / H_;
  int wave = threadIdx.x >> 6, lane = threadIdx.x & 63;
  int ln15 = lane & 15, quad = lane >> 4;
  int q0, kv0, nch;
  if (qb < 16) { q0 = qb * 64;            kv0 = NIMG_; nch = 1; }
  else         { q0 = NIMG_ + (qb-16)*64; kv0 = 0;     nch = 9; }
  int qw = q0 + wave * 16;
  const bf16* qp = Q + (size_t)(t*N_ + qw + ln15) * C_ + h*DH_ + quad*8;
  short8 aq0 = *(const short8*)qp;
  short8 aq1 = *(const short8*)(qp + 32);
  f32x4 zero = {0.f, 0.f, 0.f, 0.f};
  f32x4 oacc[4];
  #pragma unroll
  for (int d = 0; d < 4; d++) oacc[d] = zero;
  float mi[4], li[4];
  #pragma unroll
  for (int r = 0; r < 4; r++) { mi[r] = -1e30f; li[r] = 0.f; }

  for (int ch = 0; ch < nch; ch++) {
    int kb = t*N_ + kv0 + ch*128;
    #pragma unroll
    for (int i = 0; i < 4; i++) {
      int r = wave*32 + i*8;
      gll16(Kg + (size_t)(kb + r + (lane>>3))*C_ + h*DH_ + (lane&7)*8, &Ks[r][0]);
    }
    #pragma unroll
    for (int i = 0; i < 4; i++) {
      int d = wave*16 + i*4;
      gll16(Vt + ((size_t)(t*H_ + h)*64 + d + (lane>>4))*N_ + kv0 + ch*128 + ln15*8,
            &VTs[d][0]);
    }
    __syncthreads();
    // S = Q K^T * 0.125
    f32x4 s[8];
    #pragma unroll
    for (int nt = 0; nt < 8; nt++) {
      short8 b0 = *(const short8*)&Ks[nt*16 + ln15][quad*8];
      short8 b1 = *(const short8*)&Ks[nt*16 + ln15][32 + quad*8];
      f32x4 c_ = zero;
      c_ = mfma16(aq0, b0, c_);
      c_ = mfma16(aq1, b1, c_);
      #pragma unroll
      for (int r = 0; r < 4; r++) s[nt][r] = c_[r] * 0.125f;
    }
    // online softmax
    float alpha[4], lsum[4];
    #pragma unroll
    for (int r = 0; r < 4; r++) {
      float m_ = s[0][r];
      #pragma unroll
      for (int nt = 1; nt < 8; nt++) m_ = fmaxf(m_, s[nt][r]);
      #pragma unroll
      for (int o = 1; o < 16; o <<= 1) m_ = fmaxf(m_, __shfl_xor(m_, o, 64));
      float mnew = fmaxf(mi[r], m_);
      alpha[r] = __expf(mi[r] - mnew);
      mi[r] = mnew;
      lsum[r] = 0.f;
    }
    #pragma unroll
    for (int nt = 0; nt < 8; nt++)
      #pragma unroll
      for (int r = 0; r < 4; r++) {
        float p = __expf(s[nt][r] - mi[r]);
        s[nt][r] = p; lsum[r] += p;
      }
    #pragma unroll
    for (int r = 0; r < 4; r++) {
      float l_ = lsum[r];
      #pragma unroll
      for (int o = 1; o < 16; o <<= 1) l_ += __shfl_xor(l_, o, 64);
      li[r] = li[r] * alpha[r] + l_;
    }
    // P -> LDS (C-layout -> A-layout round trip)
    #pragma unroll
    for (int nt = 0; nt < 8; nt++)
      #pragma unroll
      for (int r = 0; r < 4; r++)
        Ps[wave][quad*4 + r][nt*16 + ln15] = f2b(s[nt][r]);
    #pragma unroll
    for (int d = 0; d < 4; d++)
      #pragma unroll
      for (int r = 0; r < 4; r++) oacc[d][r] *= alpha[r];
    // O += P V
    #pragma unroll
    for (int ks = 0; ks < 4; ks++) {
      short8 pa = *(const short8*)&Ps[wave][ln15][ks*32 + quad*8];
      #pragma unroll
      for (int dt = 0; dt < 4; dt++) {
        short8 vb = *(const short8*)&VTs[dt*16 + ln15][ks*32 + quad*8];
        oacc[dt] = mfma16(pa, vb, oacc[dt]);
      }
    }
    __syncthreads();
  }
  #pragma unroll
  for (int dt = 0; dt < 4; dt++)
    #pragma unroll
    for (int r = 0; r < 4; r++)
      O[(size_t)(t*N_ + qw + quad*4 + r)*C_ + h*DH_ + dt*16 + ln15]
        = f2b(oacc[dt][r] / li[r]);
}

extern "C" void kernel_launch(void* const* d_in, const int* in_sizes, int n_in,
                              void* d_out, int out_size, void* d_ws, size_t ws_size,
                              hipStream_t stream) {
  (void)in_sizes; (void)n_in; (void)out_size; (void)ws_size;
  const float* x        = (const float*)d_in[0];
  const float* tpre     = (const float*)d_in[1];
  const float* w_y      = (const float*)d_in[2];
  const float* b_y      = (const float*)d_in[3];
  const float* w_x      = (const float*)d_in[4];
  const float* b_x      = (const float*)d_in[5];
  const float* conv_w   = (const float*)d_in[6];
  const float* conv_b   = (const float*)d_in[7];
  const float* a_param  = (const float*)d_in[8];
  const float* ig_w     = (const float*)d_in[9];
  const float* ig_b     = (const float*)d_in[10];
  const float* ag_w     = (const float*)d_in[11];
  const float* ag_b     = (const float*)d_in[12];
  const float* w_out    = (const float*)d_in[13];
  const float* b_out    = (const float*)d_in[14];
  const float* cpre     = (const float*)d_in[15];
  const float* ffw_up_w = (const float*)d_in[16];
  const float* ffw_up_b = (const float*)d_in[17];
  const float* ffw_dn_w = (const float*)d_in[18];
  const float* ffw_dn_b = (const float*)d_in[19];
  const float* ln1_s    = (const float*)d_in[20];
  const float* ln1_b    = (const float*)d_in[21];
  const float* wq       = (const float*)d_in[22];
  const float* bq       = (const float*)d_in[23];
  const float* wk       = (const float*)d_in[24];
  const float* bk       = (const float*)d_in[25];
  const float* wv       = (const float*)d_in[26];
  const float* bv       = (const float*)d_in[27];
  const float* wo       = (const float*)d_in[28];
  const float* bo       = (const float*)d_in[29];
  const float* ln2_s    = (const float*)d_in[30];
  const float* ln2_b    = (const float*)d_in[31];
  const float* mlp_w1   = (const float*)d_in[32];
  const float* mlp_b1   = (const float*)d_in[33];
  const float* mlp_w2   = (const float*)d_in[34];
  const float* mlp_b2   = (const float*)d_in[35];

  const size_t MC = (size_t)M_ * C_;
  const size_t W68 = (size_t)C_ * C_;          // 589824 (768x768)
  const size_t WUP = (size_t)C_ * MLP_;        // 2.36M
  // ws layout (same 108 MB as R5): B0,B1,B2,BV bf16 M*C; F0,F1 fp32 M*C
  bf16* B0 = (bf16*)d_ws;
  bf16* B1 = B0 + MC;
  bf16* B2 = B1 + MC;
  bf16* BV = B2 + MC;
  float* F0 = (float*)(BV + MC);
  float* F1 = F0 + MC;
  bf16* F0b = (bf16*)F0;        // bf16 view for weight scratch
  float* outF = (float*)d_out;
  bf16*  gS   = (bf16*)d_out;   // g scratch during MLP1 (bf16, 4608x3072 per chunk)

  dim3 blk(256);
  dim3 gN768(C_/128, M_/128);          // (6, 72)
  dim3 cv768(12, 12);                  // convertT 768x768
  dim3 cvUp(48, 12);                   // 768x3072
  dim3 cvDn(12, 48);                   // 3072x768

  // ================= temporal RG-LRU block =================
  convertT<<<cv768, blk, 0, stream>>>(w_y, BV, C_, C_, 1, 0);                 // Wty -> BV
  convertT<<<cv768, blk, 0, stream>>>(w_x, BV + W68, C_, C_, 1, 0);           // Wtx -> BV+
  norm_kernel<0><<<M_/4, blk, 0, stream>>>(x, tpre, nullptr, B0);             // xn -> B0
  mgemm<0,1><<<gN768, blk, 0, stream>>>(B0, BV, b_y, nullptr, B1, C_, C_);    // y  -> B1
  mgemm<0,0><<<gN768, blk, 0, stream>>>(B0, BV + W68, b_x, nullptr, B2, C_, C_); // u0 -> B2
  conv_kernel<<<(M_*LRU_)/256, blk, 0, stream>>>(B2, conv_w, conv_b, B0);     // uc -> B0
  gates_kernel<<<M_*H_, 64, 0, stream>>>(B0, ig_w, ig_b, ag_w, ag_b, a_param, B2, BV); // a->B2, nx->BV
  scan_kernel<<<(N_*LRU_)/256, blk, 0, stream>>>(B2, BV, B1, B0);             // hy -> B0
  convertT<<<cv768, blk, 0, stream>>>(w_out, BV, C_, C_, 1, 0);               // Wt_out -> BV (nx dead)
  mgemm<1,0><<<gN768, blk, 0, stream>>>(B0, BV, b_out, x, F0, C_, C_);        // resid -> F0 (fp32)

  // ================= gated MLP (2 chunks of 4608 rows) =================
  norm_kernel<0><<<M_/4, blk, 0, stream>>>(F0, cpre, nullptr, B0);            // z -> B0
  convertT<<<cvUp, blk, 0, stream>>>(ffw_up_w,       B1, C_, MLP_, 2, 0);     // Wt_up interleaved -> B1
  convertT<<<cvUp, blk, 0, stream>>>(ffw_up_w + WUP, B1, C_, MLP_, 2, 1);
  convertT<<<cvDn, blk, 0, stream>>>(ffw_dn_w, BV, MLP_, C_, 1, 0);           // Wt_dn -> BV
  for (int r = 0; r < 2; r++) {
    size_t ro = (size_t)r * 4608;
    dim3 gUp(6144/128, 4608/128);   // (48, 36)
    dim3 gDn(C_/128,   4608/128);   // (6, 36)
    mgemm<3,0><<<gUp, blk, 0, stream>>>(B0 + ro*C_, B1, ffw_up_b, nullptr, gS, C_, 6144);      // g -> d_out
    mgemm<1,0><<<gDn, blk, 0, stream>>>(gS, BV, ffw_dn_b, F0 + ro*C_, F1 + ro*C_, MLP_, C_);   // xs -> F1
  }

  // ================= spatial ViT block =================
  norm_kernel<1><<<M_/4, blk, 0, stream>>>(F1, ln1_s, ln1_b, B0);             // y1 -> B0
  convertT<<<cv768, blk, 0, stream>>>(wq, F0b,          C_, C_, 1, 0);        // Wt_q..Wt_o -> F0 scratch
  convertT<<<cv768, blk, 0, stream>>>(wk, F0b + W68,    C_, C_, 1, 0);
  convertT<<<cv768, blk, 0, stream>>>(wv, F0b + 2*W68,  C_, C_, 1, 0);
  convertT<<<cv768, blk, 0, stream>>>(wo, F0b + 3*W68,  C_, C_, 1, 0);
  mgemm<0,0><<<gN768, blk, 0, stream>>>(B0, F0b,         bq, nullptr, B1, C_, C_);  // q -> B1
  mgemm<0,0><<<gN768, blk, 0, stream>>>(B0, F0b + W68,   bk, nullptr, B2, C_, C_);  // k -> B2
  mgemm<2,0><<<gN768, blk, 0, stream>>>(B0, F0b + 2*W68, bv, nullptr, BV, C_, C_);  // Vt -> BV
  fattn<<<dim3(18, T_*H_), blk, 0, stream>>>(B1, B2, BV, B0);                       // sa -> B0
  mgemm<1,0><<<gN768, blk, 0, stream>>>(B0, F0b + 3*W68, bo, F1, outF, C_, C_);     // xs2 -> d_out
  norm_kernel<1><<<M_/4, blk, 0, stream>>>(outF, ln2_s, ln2_b, BV);                 // y2 -> BV
  convertT<<<cvUp, blk, 0, stream>>>(mlp_w1, B2,       C_, MLP_, 1, 0);             // Wt_m1 -> B2
  convertT<<<cvDn, blk, 0, stream>>>(mlp_w2, B2 + WUP, MLP_, C_, 1, 0);             // Wt_m2 -> B2+
  for (int r = 0; r < 4; r++) {
    size_t ro = (size_t)r * 2304;
    dim3 gM1(MLP_/128, 2304/128);   // (24, 18)
    dim3 gM2(C_/128,   2304/128);   // (6, 18)
    mgemm<0,1><<<gM1, blk, 0, stream>>>(BV + ro*C_, B2, mlp_b1, nullptr, B0, C_, MLP_);        // m1 -> B0|B1
    mgemm<1,0><<<gM2, blk, 0, stream>>>(B0, B2 + WUP, mlp_b2, outF + ro*C_, outF + ro*C_, MLP_, C_); // out
  }
}